// Round 1
// baseline (121.996 us; speedup 1.0000x reference)
//
#include <hip/hip_runtime.h>
#include <cmath>

constexpr int NN  = 1536;  // nodes
constexpr int FF  = 512;   // in features
constexpr int HH  = 64;    // hidden
constexpr int RPB = 6;     // rows per block
constexpr int NB  = NN / RPB;  // 256 blocks

// t1 = x_init @ W1   ([1536,512] @ [512,64])
__global__ __launch_bounds__(256) void k_xw1(const float* __restrict__ x,
                                             const float* __restrict__ W,
                                             float* __restrict__ out) {
  __shared__ float xr[RPB][FF];
  __shared__ float red[4][RPB][HH];
  const int tid = threadIdx.x;
  const int i0 = blockIdx.x * RPB;
  for (int r = 0; r < RPB; ++r)
    for (int j = tid; j < FF; j += 256)
      xr[r][j] = x[(i0 + r) * FF + j];
  __syncthreads();
  const int c = tid & 63, g = tid >> 6;
  float acc[RPB] = {};
#pragma unroll 4
  for (int j = g * (FF / 4); j < (g + 1) * (FF / 4); ++j) {
    float w = W[j * HH + c];
#pragma unroll
    for (int r = 0; r < RPB; ++r) acc[r] += xr[r][j] * w;
  }
#pragma unroll
  for (int r = 0; r < RPB; ++r) red[g][r][c] = acc[r];
  __syncthreads();
  for (int idx = tid; idx < RPB * HH; idx += 256) {
    int r = idx >> 6, cc = idx & 63;
    out[(i0 + r) * HH + cc] =
        red[0][r][cc] + red[1][r][cc] + red[2][r][cc] + red[3][r][cc];
  }
}

// MODE 0: x = relu(adj@T + b);            out(A,B) = x @ Wn halves
// MODE 1: x = elu(Ain*deg + adj@T + b);   out(A,B) = x @ Wn halves
// MODE 2: x = Ain*deg + adj@T + b;        out = log_softmax(x, rows)
template <int MODE>
__global__ __launch_bounds__(256) void k_layer(
    const float* __restrict__ adj, const float* __restrict__ T,
    const float* __restrict__ Ain, const float* __restrict__ bias,
    const float* __restrict__ Wn,
    float* __restrict__ outA, float* __restrict__ outB) {
  __shared__ float arow[RPB][NN];       // 36 KB
  __shared__ float red[4][RPB][HH];     // 6 KB
  __shared__ float xloc[RPB][HH];       // 1.5 KB
  __shared__ float Wl[2 * HH][HH];      // 32 KB
  __shared__ float degs[RPB];
  const int tid = threadIdx.x;
  const int i0 = blockIdx.x * RPB;
  const int lane = tid & 63, wave = tid >> 6;

  // stage adj rows
  for (int r = 0; r < RPB; ++r)
    for (int j = tid; j < NN; j += 256)
      arow[r][j] = adj[(i0 + r) * NN + j];
  if (MODE < 2)
    for (int idx = tid; idx < 2 * HH * HH; idx += 256)
      (&Wl[0][0])[idx] = Wn[idx];
  __syncthreads();

  // deg = rowsum(adj row) from staged LDS
  if (MODE >= 1) {
    for (int r = wave; r < RPB; r += 4) {
      float v = 0.f;
      for (int j = lane; j < NN; j += 64) v += arow[r][j];
      for (int off = 32; off; off >>= 1) v += __shfl_down(v, off, 64);
      if (lane == 0) degs[r] = v;
    }
  }

  // adj @ T: wave g covers j in [g*384, (g+1)*384), lane = output col
  const int c = lane, g = wave;
  float acc[RPB] = {};
#pragma unroll 4
  for (int j = g * (NN / 4); j < (g + 1) * (NN / 4); ++j) {
    float t = T[j * HH + c];
#pragma unroll
    for (int r = 0; r < RPB; ++r) acc[r] += arow[r][j] * t;
  }
#pragma unroll
  for (int r = 0; r < RPB; ++r) red[g][r][c] = acc[r];
  __syncthreads();

  // combine partial sums + bias + deg term + activation
  for (int idx = tid; idx < RPB * HH; idx += 256) {
    int r = idx >> 6, cc = idx & 63;
    float v = red[0][r][cc] + red[1][r][cc] + red[2][r][cc] + red[3][r][cc] +
              bias[cc];
    if (MODE >= 1) v += Ain[(i0 + r) * HH + cc] * degs[r];
    if (MODE == 0) v = fmaxf(v, 0.f);
    if (MODE == 1) v = v > 0.f ? v : expm1f(v);
    xloc[r][cc] = v;
  }
  __syncthreads();

  if (MODE < 2) {
    // next layer's A = x @ Wn[:64], B = x @ Wn[64:]
    for (int idx = tid; idx < RPB * 2 * HH; idx += 256) {
      int r = idx >> 7, cc = idx & 127;
      int half = cc >> 6, col = cc & 63;
      float s = 0.f;
#pragma unroll 8
      for (int k = 0; k < HH; ++k) s += xloc[r][k] * Wl[half * HH + k][col];
      (half ? outB : outA)[(i0 + r) * HH + col] = s;
    }
  } else {
    // log_softmax per row of 64 (one wave per row)
    for (int r = wave; r < RPB; r += 4) {
      float v = xloc[r][lane];
      float m = v;
      for (int off = 32; off; off >>= 1) m = fmaxf(m, __shfl_xor(m, off, 64));
      float e = expf(v - m);
      float s = e;
      for (int off = 32; off; off >>= 1) s += __shfl_xor(s, off, 64);
      outA[(i0 + r) * HH + lane] = v - m - logf(s);
    }
  }
}

extern "C" void kernel_launch(void* const* d_in, const int* in_sizes, int n_in,
                              void* d_out, int out_size, void* d_ws,
                              size_t ws_size, hipStream_t stream) {
  const float* x_init = (const float*)d_in[0];
  const float* adj1   = (const float*)d_in[2];
  const float* W1     = (const float*)d_in[4];
  const float* b1     = (const float*)d_in[5];
  const float* W2     = (const float*)d_in[6];
  const float* b2     = (const float*)d_in[7];
  const float* W3     = (const float*)d_in[8];
  const float* b3     = (const float*)d_in[9];
  float* out = (float*)d_out;

  float* ws = (float*)d_ws;
  float* t1 = ws;                 // [1536,64]
  float* A2 = ws + 1 * NN * HH;
  float* B2 = ws + 2 * NN * HH;
  float* A3 = ws + 3 * NN * HH;
  float* B3 = ws + 4 * NN * HH;

  k_xw1<<<NB, 256, 0, stream>>>(x_init, W1, t1);
  k_layer<0><<<NB, 256, 0, stream>>>(adj1, t1, nullptr, b1, W2, A2, B2);
  k_layer<1><<<NB, 256, 0, stream>>>(adj1, B2, A2, b2, W3, A3, B3);
  k_layer<2><<<NB, 256, 0, stream>>>(adj1, B3, A3, b3, nullptr, out, nullptr);
}

// Round 2
// 42.936 us; speedup vs baseline: 2.8413x; 2.8413x over previous
//
#include <hip/hip_runtime.h>
#include <cmath>

constexpr int NN    = 1536;  // nodes
constexpr int FF    = 512;   // in features
constexpr int HH    = 64;    // hidden
constexpr int RPB   = 6;     // rows per block
constexpr int NB    = NN / RPB;  // 256 blocks
constexpr int NT    = 512;   // threads per block (8 waves)
constexpr int WAVES = NT / 64;

__device__ __forceinline__ void wave_reduce_g4(float4& v) {
  // sum across the 4 lane-groups (lane>>4): xor 16, then 32
  v.x += __shfl_xor(v.x, 16, 64); v.y += __shfl_xor(v.y, 16, 64);
  v.z += __shfl_xor(v.z, 16, 64); v.w += __shfl_xor(v.w, 16, 64);
  v.x += __shfl_xor(v.x, 32, 64); v.y += __shfl_xor(v.y, 32, 64);
  v.z += __shfl_xor(v.z, 32, 64); v.w += __shfl_xor(v.w, 32, 64);
}

// t1 = x_init @ W1   ([1536,512] @ [512,64])
__global__ __launch_bounds__(NT) void k_xw1(const float* __restrict__ x,
                                            const float* __restrict__ W,
                                            float* __restrict__ out) {
  __shared__ float xr[RPB * FF];                // 12 KB
  __shared__ float red[WAVES][RPB][HH];         // 12 KB
  const int tid = threadIdx.x;
  const int i0 = blockIdx.x * RPB;
  const int lane = tid & 63, wave = tid >> 6;

  {
    const float4* src = (const float4*)(x + (size_t)i0 * FF);
    float4* dst = (float4*)xr;
    for (int idx = tid; idx < RPB * FF / 4; idx += NT) dst[idx] = src[idx];
  }
  __syncthreads();

  const int g4 = lane >> 4, c4 = (lane & 15) * 4;
  float4 acc[RPB];
#pragma unroll
  for (int r = 0; r < RPB; ++r) acc[r] = make_float4(0.f, 0.f, 0.f, 0.f);

  const int jbeg = wave * (FF / WAVES);  // 64 per wave
#pragma unroll 4
  for (int j = jbeg; j < jbeg + FF / WAVES; j += 4) {
    float4 t = *(const float4*)(W + (size_t)(j + g4) * HH + c4);
#pragma unroll
    for (int r = 0; r < RPB; ++r) {
      float a = xr[r * FF + j + g4];
      acc[r].x = fmaf(a, t.x, acc[r].x);
      acc[r].y = fmaf(a, t.y, acc[r].y);
      acc[r].z = fmaf(a, t.z, acc[r].z);
      acc[r].w = fmaf(a, t.w, acc[r].w);
    }
  }
#pragma unroll
  for (int r = 0; r < RPB; ++r) {
    wave_reduce_g4(acc[r]);
    if (lane < 16) *(float4*)&red[wave][r][lane * 4] = acc[r];
  }
  __syncthreads();

  if (tid < RPB * HH) {
    int r = tid >> 6, c = tid & 63;
    float v = 0.f;
#pragma unroll
    for (int w = 0; w < WAVES; ++w) v += red[w][r][c];
    out[(size_t)(i0 + r) * HH + c] = v;
  }
}

// MODE 0: x = relu(adj@T + b);            outA/outB = x @ Wn halves
// MODE 1: x = elu(Ain*deg + adj@T + b);   outA/outB = x @ Wn halves
// MODE 2: x = Ain*deg + adj@T + b;        outA = log_softmax(x, rows)
template <int MODE>
__global__ __launch_bounds__(NT) void k_layer(
    const float* __restrict__ adj, const float* __restrict__ T,
    const float* __restrict__ Ain, const float* __restrict__ bias,
    const float* __restrict__ Wn,
    float* __restrict__ outA, float* __restrict__ outB) {
  __shared__ float arow[RPB * NN];              // 36 KB
  __shared__ float red[WAVES][RPB][HH];         // 12 KB
  __shared__ float xloc[RPB][HH];               // 1.5 KB
  __shared__ float Wl[2 * HH * HH];             // 32 KB (MODE<2)
  __shared__ float degs[RPB];
  const int tid = threadIdx.x;
  const int i0 = blockIdx.x * RPB;
  const int lane = tid & 63, wave = tid >> 6;

  // stage the 6-row adj slab (contiguous in global)
  {
    const float4* src = (const float4*)(adj + (size_t)i0 * NN);
    float4* dst = (float4*)arow;
    for (int idx = tid; idx < RPB * NN / 4; idx += NT) dst[idx] = src[idx];
  }
  if (MODE < 2) {
    const float4* src = (const float4*)Wn;
    float4* dst = (float4*)Wl;
    for (int idx = tid; idx < 2 * HH * HH / 4; idx += NT) dst[idx] = src[idx];
  }
  __syncthreads();

  // deg = rowsum(adj row), one wave per row
  if (MODE >= 1 && wave < RPB) {
    float v = 0.f;
    for (int j = lane; j < NN; j += 64) v += arow[wave * NN + j];
#pragma unroll
    for (int off = 32; off; off >>= 1) v += __shfl_xor(v, off, 64);
    if (lane == 0) degs[wave] = v;
  }

  // adj @ T: wave w covers j in [w*192, (w+1)*192); lane loads float4 of T
  const int g4 = lane >> 4, c4 = (lane & 15) * 4;
  float4 acc[RPB];
#pragma unroll
  for (int r = 0; r < RPB; ++r) acc[r] = make_float4(0.f, 0.f, 0.f, 0.f);

  const int jbeg = wave * (NN / WAVES);  // 192 per wave
#pragma unroll 4
  for (int j = jbeg; j < jbeg + NN / WAVES; j += 4) {
    float4 t = *(const float4*)(T + (size_t)(j + g4) * HH + c4);
#pragma unroll
    for (int r = 0; r < RPB; ++r) {
      float a = arow[r * NN + j + g4];
      acc[r].x = fmaf(a, t.x, acc[r].x);
      acc[r].y = fmaf(a, t.y, acc[r].y);
      acc[r].z = fmaf(a, t.z, acc[r].z);
      acc[r].w = fmaf(a, t.w, acc[r].w);
    }
  }
#pragma unroll
  for (int r = 0; r < RPB; ++r) {
    wave_reduce_g4(acc[r]);
    if (lane < 16) *(float4*)&red[wave][r][lane * 4] = acc[r];
  }
  __syncthreads();

  // combine waves + bias + deg term + activation
  if (tid < RPB * HH) {
    int r = tid >> 6, c = tid & 63;
    float v = bias[c];
#pragma unroll
    for (int w = 0; w < WAVES; ++w) v += red[w][r][c];
    if (MODE >= 1) v += Ain[(size_t)(i0 + r) * HH + c] * degs[r];
    if (MODE == 0) v = fmaxf(v, 0.f);
    if (MODE == 1) v = v > 0.f ? v : expm1f(v);
    xloc[r][c] = v;
  }
  __syncthreads();

  if (MODE < 2) {
    // next layer's A = x @ Wn[:64], B = x @ Wn[64:]
    for (int idx = tid; idx < RPB * 2 * HH; idx += NT) {
      int r = idx >> 7, cc = idx & 127;
      int half = cc >> 6, col = cc & 63;
      float s = 0.f;
#pragma unroll
      for (int k = 0; k < HH; ++k)
        s = fmaf(xloc[r][k], Wl[(half * HH + k) * HH + col], s);
      (half ? outB : outA)[(size_t)(i0 + r) * HH + col] = s;
    }
  } else {
    // log_softmax per row (one wave per row)
    if (wave < RPB) {
      float v = xloc[wave][lane];
      float m = v;
#pragma unroll
      for (int off = 32; off; off >>= 1) m = fmaxf(m, __shfl_xor(m, off, 64));
      float e = expf(v - m);
      float s = e;
#pragma unroll
      for (int off = 32; off; off >>= 1) s += __shfl_xor(s, off, 64);
      outA[(size_t)(i0 + wave) * HH + lane] = v - m - logf(s);
    }
  }
}

extern "C" void kernel_launch(void* const* d_in, const int* in_sizes, int n_in,
                              void* d_out, int out_size, void* d_ws,
                              size_t ws_size, hipStream_t stream) {
  const float* x_init = (const float*)d_in[0];
  const float* adj1   = (const float*)d_in[2];
  const float* W1     = (const float*)d_in[4];
  const float* b1     = (const float*)d_in[5];
  const float* W2     = (const float*)d_in[6];
  const float* b2     = (const float*)d_in[7];
  const float* W3     = (const float*)d_in[8];
  const float* b3     = (const float*)d_in[9];
  float* out = (float*)d_out;

  float* ws = (float*)d_ws;
  float* t1 = ws;                 // [1536,64]
  float* A2 = ws + 1 * NN * HH;
  float* B2 = ws + 2 * NN * HH;
  float* A3 = ws + 3 * NN * HH;
  float* B3 = ws + 4 * NN * HH;

  k_xw1<<<NB, NT, 0, stream>>>(x_init, W1, t1);
  k_layer<0><<<NB, NT, 0, stream>>>(adj1, t1, nullptr, b1, W2, A2, B2);
  k_layer<1><<<NB, NT, 0, stream>>>(adj1, B2, A2, b2, W3, A3, B3);
  k_layer<2><<<NB, NT, 0, stream>>>(adj1, B3, A3, b3, nullptr, out, nullptr);
}